// Round 2
// baseline (71.502 us; speedup 1.0000x reference)
//
#include <hip/hip_runtime.h>

// UFLAttention collapses algebraically: softmax over the contracted key axis
// sums to 1, so combined[b,i] = (x[b,i]*sum_h(Wv[i,h]) + sum_h(bv[i,h]))/sqrt(D).
// y = relu(x + combined); out = layernorm_D(y)*gamma + beta.
// Wq/bq/Wk/bk are never read.
//
// Layout: 128 blocks x 256 threads. Each wave (64 lanes) owns one batch row;
// each lane owns 4 consecutive features via float4. Row reduction = 6-step
// __shfl_xor within the wave — no LDS, no __syncthreads.

constexpr int B_DIM = 512;
constexpr int D_DIM = 256;

__global__ __launch_bounds__(256) void ufl_collapsed_kernel(
    const float* __restrict__ x,      // [B, D]
    const float* __restrict__ Wv,     // [D, H=8]
    const float* __restrict__ bv,     // [D, H=8]
    const float* __restrict__ gamma,  // [D]
    const float* __restrict__ beta,   // [D]
    float* __restrict__ out)          // [B, D]
{
    const int wave = threadIdx.x >> 6;          // 0..3
    const int lane = threadIdx.x & 63;          // 0..63
    const int row  = blockIdx.x * 4 + wave;     // batch row, 0..511

    const float4* __restrict__ x4  = (const float4*)x;
    const float4* __restrict__ w4  = (const float4*)Wv;   // row r = slots 2r, 2r+1
    const float4* __restrict__ b4  = (const float4*)bv;
    const float4* __restrict__ g4  = (const float4*)gamma;
    const float4* __restrict__ bt4 = (const float4*)beta;
    float4* __restrict__ o4 = (float4*)out;

    const float4 xv = x4[row * 64 + lane];      // features 4*lane .. 4*lane+3
    const float xs[4] = {xv.x, xv.y, xv.z, xv.w};

    // Per-feature head-sums of Wv and bv: 32 contiguous floats at 32*lane.
    const int base = lane * 8;
    float yv[4];
    float s = 0.0f, ss = 0.0f;
#pragma unroll
    for (int j = 0; j < 4; ++j) {
        const float4 wa = w4[base + 2 * j], wb = w4[base + 2 * j + 1];
        const float4 ba = b4[base + 2 * j], bb = b4[base + 2 * j + 1];
        const float sw = wa.x + wa.y + wa.z + wa.w + wb.x + wb.y + wb.z + wb.w;
        const float sb = ba.x + ba.y + ba.z + ba.w + bb.x + bb.y + bb.z + bb.w;
        const float combined = (xs[j] * sw + sb) * 0.0625f;  // / sqrt(256)
        const float y = fmaxf(xs[j] + combined, 0.0f);
        yv[j] = y;
        s  += y;
        ss += y * y;
    }

    // Wave-wide butterfly reduction (64 lanes) — every lane ends with totals.
#pragma unroll
    for (int off = 32; off >= 1; off >>= 1) {
        s  += __shfl_xor(s,  off, 64);
        ss += __shfl_xor(ss, off, 64);
    }

    const float mu  = s * (1.0f / D_DIM);
    const float var = ss * (1.0f / D_DIM) - mu * mu;
    const float inv = 1.0f / sqrtf(var + 1e-5f);

    const float4 g = g4[lane], bt = bt4[lane];
    float4 o;
    o.x = (yv[0] - mu) * inv * g.x + bt.x;
    o.y = (yv[1] - mu) * inv * g.y + bt.y;
    o.z = (yv[2] - mu) * inv * g.z + bt.z;
    o.w = (yv[3] - mu) * inv * g.w + bt.w;
    o4[row * 64 + lane] = o;
}

extern "C" void kernel_launch(void* const* d_in, const int* in_sizes, int n_in,
                              void* d_out, int out_size, void* d_ws, size_t ws_size,
                              hipStream_t stream) {
    // setup_inputs order: x, Wq, bq, Wk, bk, Wv, bv, gamma, beta
    const float* x     = (const float*)d_in[0];
    const float* Wv    = (const float*)d_in[5];
    const float* bv    = (const float*)d_in[6];
    const float* gamma = (const float*)d_in[7];
    const float* beta  = (const float*)d_in[8];
    float* out = (float*)d_out;

    ufl_collapsed_kernel<<<B_DIM / 4, 256, 0, stream>>>(x, Wv, bv, gamma, beta, out);
}